// Round 6
// baseline (470.087 us; speedup 1.0000x reference)
//
#include <hip/hip_runtime.h>
#include <math.h>

#define DIN 128
#define HD 64
#define NEG 0.2f

__device__ __forceinline__ float sigmoidf_(float x) { return 1.f / (1.f + __expf(-x)); }
__device__ __forceinline__ float tanhf_(float x)    { return 2.f / (1.f + __expf(-2.f*x)) - 1.f; }

// ---------------- CSR build ----------------
__global__ void k_count(const int* __restrict__ dst, int E, int* __restrict__ deg) {
  int e = blockIdx.x*256 + threadIdx.x;
  if (e < E) atomicAdd(&deg[dst[e]], 1);
}

__global__ void k_scan1(const int* __restrict__ deg, int n, int* __restrict__ rowst, int* __restrict__ bsum) {
  __shared__ int s[256];
  int i = blockIdx.x*256 + threadIdx.x;
  int v = (i < n) ? deg[i] : 0;
  s[threadIdx.x] = v;
  __syncthreads();
  for (int off = 1; off < 256; off <<= 1) {
    int t = (threadIdx.x >= off) ? s[threadIdx.x - off] : 0;
    __syncthreads();
    s[threadIdx.x] += t;
    __syncthreads();
  }
  if (i < n) rowst[i] = s[threadIdx.x] - v;
  if (threadIdx.x == 255) bsum[blockIdx.x] = s[255];
}

__global__ void k_scan2(int* bsum, int nb) {
  __shared__ int s[256];
  int v = (threadIdx.x < nb) ? bsum[threadIdx.x] : 0;
  s[threadIdx.x] = v;
  __syncthreads();
  for (int off = 1; off < 256; off <<= 1) {
    int t = (threadIdx.x >= off) ? s[threadIdx.x - off] : 0;
    __syncthreads();
    s[threadIdx.x] += t;
    __syncthreads();
  }
  if (threadIdx.x < nb) bsum[threadIdx.x] = s[threadIdx.x] - v;
}

__global__ void k_scan3(int* __restrict__ rowst, const int* __restrict__ bsum, int n, int E, int* __restrict__ deg) {
  int i = blockIdx.x*256 + threadIdx.x;
  if (i < n) { rowst[i] += bsum[blockIdx.x]; deg[i] = 0; }
  if (i == 0) rowst[n] = E;
}

__global__ void k_scatter(const int* __restrict__ src, const int* __restrict__ dst, int E,
                          const int* __restrict__ rowst, int* __restrict__ fill, int* __restrict__ csr) {
  int e = blockIdx.x*256 + threadIdx.x;
  if (e < E) {
    int d = dst[e];
    int pos = rowst[d] + atomicAdd(&fill[d], 1);
    csr[pos] = src[e];
  }
}

// ---------------- GRU weight re-layout ----------------
// B[k][c], k in [0,128): k<64 -> m-row (Wi), k>=64 -> h-row (Wh).
// c = j*4 + gate; gate 0: r-sum, 1: z-sum, 2: gi_n (Wi only), 3: gh_n (Wh only)
__global__ void k_wt2(const float* __restrict__ Wi, const float* __restrict__ Wh,
                      const float* __restrict__ bi, const float* __restrict__ bh,
                      float* __restrict__ B, float* __restrict__ bc) {
  int i = blockIdx.x*256 + threadIdx.x;
  if (i < 128*256) {
    int k = i >> 8, c = i & 255;
    int j = c >> 2, g = c & 3;
    float v;
    if (g == 0)      v = (k < 64) ? Wi[k*(3*HD) + j]        : Wh[(k-64)*(3*HD) + j];
    else if (g == 1) v = (k < 64) ? Wi[k*(3*HD) + HD + j]   : Wh[(k-64)*(3*HD) + HD + j];
    else if (g == 2) v = (k < 64) ? Wi[k*(3*HD) + 2*HD + j] : 0.f;
    else             v = (k < 64) ? 0.f                     : Wh[(k-64)*(3*HD) + 2*HD + j];
    B[i] = v;
  }
  if (i < 256) {
    int j = i >> 2, g = i & 3;
    float v;
    if (g == 0)      v = bi[j] + bh[j];
    else if (g == 1) v = bi[HD + j] + bh[HD + j];
    else if (g == 2) v = bi[2*HD + j];
    else             v = bh[2*HD + j];
    bc[i] = v;
  }
}

// ---------------- input projection as register-blocked GEMM (M=32 tile) ----------------
__global__ void __launch_bounds__(256) k_proj2(const float* __restrict__ x, const float* __restrict__ Win,
                       const float* __restrict__ bin, const float* __restrict__ aatt, int n,
                       float* __restrict__ h, float* __restrict__ ssrc, float* __restrict__ sdst) {
  __shared__ float A[DIN][32];   // 16KB
  int m_base = blockIdx.x * 32;
  int tx = threadIdx.x;
  {
    int m = tx & 31;
    int kq8 = tx >> 5;           // 0..7
    int node = m_base + m;
    bool valid = node < n;
    const float4* x4 = (const float4*)(x + (size_t)node*DIN);
#pragma unroll
    for (int it = 0; it < 4; ++it) {
      int kq = kq8*4 + it;       // 0..31
      int k0 = kq*4;
      float4 v = make_float4(0.f,0.f,0.f,0.f);
      if (valid) v = x4[kq];
      A[k0+0][m] = v.x; A[k0+1][m] = v.y; A[k0+2][m] = v.z; A[k0+3][m] = v.w;
    }
  }
  __syncthreads();

  int c_idx = tx & 31;           // 2 cols each
  int m_idx = tx >> 5;           // 8 node groups of 4
  int c0 = c_idx * 2;
  int m0 = m_idx * 4;

  float acc[4][2];
#pragma unroll
  for (int a = 0; a < 4; ++a) { acc[a][0] = 0.f; acc[a][1] = 0.f; }

#pragma unroll 4
  for (int k = 0; k < DIN; ++k) {
    float2 b = *(const float2*)(Win + k*HD + c0);
    float4 a0 = *(const float4*)(&A[k][m0]);
    float av[4] = {a0.x,a0.y,a0.z,a0.w};
#pragma unroll
    for (int a = 0; a < 4; ++a) { acc[a][0] += av[a]*b.x; acc[a][1] += av[a]*b.y; }
  }

  float b0 = bin[c0], b1 = bin[c0+1];
  float a_s0 = aatt[c0],    a_s1 = aatt[c0+1];
  float a_d0 = aatt[HD+c0], a_d1 = aatt[HD+c0+1];

#pragma unroll
  for (int a = 0; a < 4; ++a) {
    int node = m_base + m0 + a;
    float v0 = fmaxf(acc[a][0] + b0, 0.f);
    float v1 = fmaxf(acc[a][1] + b1, 0.f);
    if (node < n) {
      h[(size_t)node*HD + c0]   = v0;
      h[(size_t)node*HD + c0+1] = v1;
    }
    float ps = v0*a_s0 + v1*a_s1;
    float pd = v0*a_d0 + v1*a_d1;
#pragma unroll
    for (int off = 16; off; off >>= 1) { ps += __shfl_xor(ps, off); pd += __shfl_xor(pd, off); }
    if (c_idx == 0 && node < n) { ssrc[node] = ps; sdst[node] = pd; }
  }
}

// ---------------- attention scores: 16-lane group per node ----------------
__global__ void k_score(const float* __restrict__ ssrc, const float* __restrict__ sdst,
                        const int* __restrict__ rowst, const int* __restrict__ csr, int n,
                        float* __restrict__ alpha, float* __restrict__ z) {
  int g16 = threadIdx.x >> 4;
  int l16 = threadIdx.x & 15;
  int node = blockIdx.x*16 + g16;
  if (node >= n) return;
  int s0 = rowst[node], s1 = rowst[node+1];
  float sdv = sdst[node];
  float mx = -INFINITY;
  for (int i = s0 + l16; i < s1; i += 16) {
    float sc = ssrc[csr[i]] + sdv;
    sc = (sc > 0.f) ? sc : NEG*sc;
    alpha[i] = sc;
    mx = fmaxf(mx, sc);
  }
#pragma unroll
  for (int off = 8; off; off >>= 1) mx = fmaxf(mx, __shfl_xor(mx, off));
  float zs = 0.f;
  for (int i = s0 + l16; i < s1; i += 16) {
    float e = __expf(alpha[i] - mx);
    alpha[i] = e;
    zs += e;
  }
#pragma unroll
  for (int off = 8; off; off >>= 1) zs += __shfl_xor(zs, off);
  if (l16 == 0) z[node] = zs;
}

// ---------------- gather pass: 2 nodes per wave (32-lane halves, float2/lane), 4 edges in flight ----------------
__global__ void k_agg3(const float* __restrict__ h, const float* __restrict__ alpha,
                       const float* __restrict__ z, const int* __restrict__ rowst,
                       const int* __restrict__ csr, int n, float* __restrict__ mout) {
  int wid = threadIdx.x >> 6;
  int lane = threadIdx.x & 63;
  int half = lane >> 5, l32 = lane & 31;
  int node = blockIdx.x*8 + wid*2 + half;
  if (node >= n) return;
  int s0 = rowst[node], s1 = rowst[node+1];
  float2 acc0 = make_float2(0.f,0.f), acc1 = make_float2(0.f,0.f);
  float2 acc2 = make_float2(0.f,0.f), acc3 = make_float2(0.f,0.f);
  int i = s0;
  for (; i + 3 < s1; i += 4) {
    int u0 = csr[i], u1 = csr[i+1], u2 = csr[i+2], u3 = csr[i+3];
    float a0 = alpha[i], a1 = alpha[i+1], a2 = alpha[i+2], a3 = alpha[i+3];
    float2 h0 = *((const float2*)(h + (size_t)u0*HD) + l32);
    float2 h1 = *((const float2*)(h + (size_t)u1*HD) + l32);
    float2 h2 = *((const float2*)(h + (size_t)u2*HD) + l32);
    float2 h3 = *((const float2*)(h + (size_t)u3*HD) + l32);
    acc0.x += a0*h0.x; acc0.y += a0*h0.y;
    acc1.x += a1*h1.x; acc1.y += a1*h1.y;
    acc2.x += a2*h2.x; acc2.y += a2*h2.y;
    acc3.x += a3*h3.x; acc3.y += a3*h3.y;
  }
  for (; i < s1; ++i) {
    float a0 = alpha[i];
    float2 h0 = *((const float2*)(h + (size_t)csr[i]*HD) + l32);
    acc0.x += a0*h0.x; acc0.y += a0*h0.y;
  }
  float zi = 1.f / (z[node] + 1e-16f);
  float2 r;
  r.x = ((acc0.x + acc1.x) + (acc2.x + acc3.x)) * zi;
  r.y = ((acc0.y + acc1.y) + (acc2.y + acc3.y)) * zi;
  *((float2*)(mout + (size_t)node*HD) + l32) = r;
}

// ---------------- GRU GEMM v4: lane-per-column mapping, M=64 tile ----------------
// 256 threads = 4 waves. Lane owns column group c0 = 4*lane (one j = lane, 4 gates).
// Each thread computes 16 nodes (m0 = (tx>>6)*16). Per k: ONE coalesced B float4 per lane
// (1KB unique per wave) + 4 broadcast LDS float4 of A. acc[16][4].
__global__ void __launch_bounds__(256, 3) k_gru4(const float* __restrict__ mm, float* __restrict__ h,
                      const float* __restrict__ B, const float* __restrict__ bc,
                      const float* __restrict__ aatt, int n,
                      float* __restrict__ ssrc, float* __restrict__ sdst) {
  __shared__ float A[128][64];   // 32KB: rows 0..63 = m, rows 64..127 = h
  int m_base = blockIdx.x * 64;
  int tx = threadIdx.x;
  {
    int m = tx & 63;
    int kq4 = tx >> 6;           // 0..3
    int node = m_base + m;
    bool valid = node < n;
    const float4* m4 = (const float4*)(mm + (size_t)node*HD);
    const float4* h4 = (const float4*)(h  + (size_t)node*HD);
#pragma unroll
    for (int it = 0; it < 8; ++it) {
      int kq = kq4*8 + it;       // 0..31
      int k0 = kq*4;
      float4 v = make_float4(0.f,0.f,0.f,0.f);
      if (valid) v = (kq < 16) ? m4[kq] : h4[kq - 16];
      A[k0+0][m] = v.x; A[k0+1][m] = v.y; A[k0+2][m] = v.z; A[k0+3][m] = v.w;
    }
  }
  __syncthreads();

  int lane = tx & 63;            // j = lane
  int m0 = (tx >> 6) * 16;       // 16 nodes per thread

  float acc[16][4];
#pragma unroll
  for (int a = 0; a < 16; ++a)
#pragma unroll
    for (int b = 0; b < 4; ++b) acc[a][b] = 0.f;

  const float4* Bv = (const float4*)B;   // row k: Bv[k*64 + lane]

  // prologue: k = 0
  float4 bcur = Bv[lane];
  float4 ac0 = *(const float4*)(&A[0][m0]);
  float4 ac1 = *(const float4*)(&A[0][m0+4]);
  float4 ac2 = *(const float4*)(&A[0][m0+8]);
  float4 ac3 = *(const float4*)(&A[0][m0+12]);

#pragma unroll 1
  for (int k = 0; k < 127; ++k) {
    float4 bn  = Bv[(size_t)(k+1)*64 + lane];
    float4 an0 = *(const float4*)(&A[k+1][m0]);
    float4 an1 = *(const float4*)(&A[k+1][m0+4]);
    float4 an2 = *(const float4*)(&A[k+1][m0+8]);
    float4 an3 = *(const float4*)(&A[k+1][m0+12]);
    float av[16] = {ac0.x,ac0.y,ac0.z,ac0.w, ac1.x,ac1.y,ac1.z,ac1.w,
                    ac2.x,ac2.y,ac2.z,ac2.w, ac3.x,ac3.y,ac3.z,ac3.w};
#pragma unroll
    for (int a = 0; a < 16; ++a) {
      acc[a][0] += av[a]*bcur.x;
      acc[a][1] += av[a]*bcur.y;
      acc[a][2] += av[a]*bcur.z;
      acc[a][3] += av[a]*bcur.w;
    }
    bcur = bn; ac0 = an0; ac1 = an1; ac2 = an2; ac3 = an3;
  }
  { // k = 127
    float av[16] = {ac0.x,ac0.y,ac0.z,ac0.w, ac1.x,ac1.y,ac1.z,ac1.w,
                    ac2.x,ac2.y,ac2.z,ac2.w, ac3.x,ac3.y,ac3.z,ac3.w};
#pragma unroll
    for (int a = 0; a < 16; ++a) {
      acc[a][0] += av[a]*bcur.x;
      acc[a][1] += av[a]*bcur.y;
      acc[a][2] += av[a]*bcur.z;
      acc[a][3] += av[a]*bcur.w;
    }
  }

  float4 bcr = *(const float4*)(bc + 4*lane);
  float a_s = aatt[lane];
  float a_d = aatt[HD + lane];

#pragma unroll
  for (int a = 0; a < 16; ++a) {
    int node = m_base + m0 + a;
    float hold = (node < n) ? h[(size_t)node*HD + lane] : 0.f;
    float r   = acc[a][0] + bcr.x;
    float zz  = acc[a][1] + bcr.y;
    float gin = acc[a][2] + bcr.z;
    float ghn = acc[a][3] + bcr.w;
    float rg = sigmoidf_(r);
    float zg = sigmoidf_(zz);
    float ng = tanhf_(gin + rg*ghn);
    float hnew = (1.f - zg)*ng + zg*hold;
    if (node < n) h[(size_t)node*HD + lane] = hnew;
    float ps = hnew * a_s;
    float pd = hnew * a_d;
#pragma unroll
    for (int off = 32; off; off >>= 1) { ps += __shfl_xor(ps, off); pd += __shfl_xor(pd, off); }
    if (lane == 0 && node < n) { ssrc[node] = ps; sdst[node] = pd; }
  }
}

// ---------------- pooling: two-stage ----------------
__device__ __forceinline__ int lower_bound_i(const int* a, int n, int key) {
  int lo = 0, hi = n;
  while (lo < hi) { int mid = (lo + hi) >> 1; if (a[mid] < key) lo = mid + 1; else hi = mid; }
  return lo;
}

__global__ void k_pool1(const float* __restrict__ h, const int* __restrict__ batch, int n,
                        float* __restrict__ psum, float* __restrict__ pmax) {
  int g = blockIdx.x >> 3, slice = blockIdx.x & 7;
  int lane = threadIdx.x;            // 64 lanes = HD
  int lo = lower_bound_i(batch, n, g);
  int hi = lower_bound_i(batch, n, g + 1);
  int span = hi - lo;
  int s0 = lo + (int)(((long long)span * slice) >> 3);
  int s1 = lo + (int)(((long long)span * (slice + 1)) >> 3);
  float sum0 = 0.f, sum1 = 0.f, sum2 = 0.f, sum3 = 0.f;
  float mx0 = -INFINITY, mx1 = -INFINITY, mx2 = -INFINITY, mx3 = -INFINITY;
  int i = s0;
  for (; i + 3 < s1; i += 4) {
    float v0 = h[(size_t)(i+0)*HD + lane];
    float v1 = h[(size_t)(i+1)*HD + lane];
    float v2 = h[(size_t)(i+2)*HD + lane];
    float v3 = h[(size_t)(i+3)*HD + lane];
    sum0 += v0; sum1 += v1; sum2 += v2; sum3 += v3;
    mx0 = fmaxf(mx0, v0); mx1 = fmaxf(mx1, v1); mx2 = fmaxf(mx2, v2); mx3 = fmaxf(mx3, v3);
  }
  for (; i < s1; ++i) {
    float v = h[(size_t)i*HD + lane];
    sum0 += v; mx0 = fmaxf(mx0, v);
  }
  float sum = (sum0 + sum1) + (sum2 + sum3);
  float mx = fmaxf(fmaxf(mx0, mx1), fmaxf(mx2, mx3));
  psum[(size_t)blockIdx.x*HD + lane] = sum;
  pmax[(size_t)blockIdx.x*HD + lane] = mx;
}

__global__ void k_pool2(const float* __restrict__ psum, const float* __restrict__ pmax,
                        const int* __restrict__ batch, int n, float* __restrict__ gpool) {
  int g = blockIdx.x;
  int lane = threadIdx.x;
  int lo = lower_bound_i(batch, n, g);
  int hi = lower_bound_i(batch, n, g + 1);
  int cnt = hi - lo;
  float sum = 0.f, mx = -INFINITY;
#pragma unroll
  for (int s = 0; s < 8; ++s) {
    sum += psum[(size_t)(g*8+s)*HD + lane];
    mx = fmaxf(mx, pmax[(size_t)(g*8+s)*HD + lane]);
  }
  float mean = sum / fmaxf((float)cnt, 1.f);
  if (cnt <= 0 || !isfinite(mx)) mx = 0.f;
  gpool[(size_t)g*2*HD + lane] = mean;
  gpool[(size_t)g*2*HD + HD + lane] = mx;
}

// ---------------- MLP head (block per graph, one wave) ----------------
__global__ void k_head(const float* __restrict__ gpool, const float* __restrict__ W1,
                       const float* __restrict__ b1, const float* __restrict__ W2,
                       const float* __restrict__ b2, float* __restrict__ out) {
  int g = blockIdx.x, j = threadIdx.x;
  const float* gr = gpool + (size_t)g*2*HD;
  float acc = b1[j];
#pragma unroll
  for (int k = 0; k < 2*HD; ++k) acc += gr[k] * W1[k*HD + j];
  acc = fmaxf(acc, 0.f);
  float v = acc * W2[j];
#pragma unroll
  for (int off = 32; off; off >>= 1) v += __shfl_xor(v, off);
  if (j == 0) out[g] = v + b2[0];
}

extern "C" void kernel_launch(void* const* d_in, const int* in_sizes, int n_in,
                              void* d_out, int out_size, void* d_ws, size_t ws_size,
                              hipStream_t stream) {
  const float* x     = (const float*)d_in[0];
  const int*   ei    = (const int*)d_in[1];
  const int*   batch = (const int*)d_in[2];
  const float* Win   = (const float*)d_in[3];
  const float* bin   = (const float*)d_in[4];
  const float* aatt  = (const float*)d_in[5];
  const float* Wi    = (const float*)d_in[6];
  const float* Wh    = (const float*)d_in[7];
  const float* bi    = (const float*)d_in[8];
  const float* bh    = (const float*)d_in[9];
  const float* W1    = (const float*)d_in[10];
  const float* b1    = (const float*)d_in[11];
  const float* W2    = (const float*)d_in[12];
  const float* b2    = (const float*)d_in[13];
  float* out = (float*)d_out;

  int N = in_sizes[0] / DIN;
  int E = in_sizes[1] / 2;
  int G = out_size;

  const int* srcp = ei;
  const int* dstp = ei + E;

  char* base = (char*)d_ws;
  size_t off = 0;
  auto alloc = [&](size_t bytes) -> char* {
    char* p = base + off;
    off += (bytes + 255) & ~(size_t)255;
    return p;
  };
  float* h     = (float*)alloc((size_t)N*HD*4);
  float* mbuf  = (float*)alloc((size_t)N*HD*4);
  float* ssrc  = (float*)alloc((size_t)N*4);
  float* sdst  = (float*)alloc((size_t)N*4);
  int*   deg   = (int*)  alloc((size_t)N*4);
  int*   rowst = (int*)  alloc((size_t)(N+1)*4);
  int*   csr   = (int*)  alloc((size_t)E*4);
  float* alpha = (float*)alloc((size_t)E*4);
  float* zbuf  = (float*)alloc((size_t)N*4);
  float* B     = (float*)alloc((size_t)128*256*4);
  float* bc    = (float*)alloc((size_t)256*4);
  float* gpool = (float*)alloc((size_t)G*2*HD*4);
  float* psum  = (float*)alloc((size_t)G*8*HD*4);
  float* pmax  = (float*)alloc((size_t)G*8*HD*4);
  int*   bsum  = (int*)  alloc(1024);
  (void)ws_size; (void)n_in;

  int nbN = (N + 255)/256, nbE = (E + 255)/256;

  hipMemsetAsync(deg, 0, (size_t)N*4, stream);
  k_count<<<nbE, 256, 0, stream>>>(dstp, E, deg);
  k_scan1<<<nbN, 256, 0, stream>>>(deg, N, rowst, bsum);
  k_scan2<<<1, 256, 0, stream>>>(bsum, nbN);
  k_scan3<<<nbN, 256, 0, stream>>>(rowst, bsum, N, E, deg);
  k_scatter<<<nbE, 256, 0, stream>>>(srcp, dstp, E, rowst, deg, csr);
  k_wt2<<<(128*256 + 255)/256, 256, 0, stream>>>(Wi, Wh, bi, bh, B, bc);
  k_proj2<<<(N + 31)/32, 256, 0, stream>>>(x, Win, bin, aatt, N, h, ssrc, sdst);
  for (int t = 0; t < 3; ++t) {
    k_score<<<(N + 15)/16, 256, 0, stream>>>(ssrc, sdst, rowst, csr, N, alpha, zbuf);
    k_agg3<<<(N + 7)/8, 256, 0, stream>>>(h, alpha, zbuf, rowst, csr, N, mbuf);
    k_gru4<<<(N + 63)/64, 256, 0, stream>>>(mbuf, h, B, bc, aatt, N, ssrc, sdst);
  }
  k_pool1<<<G*8, 64, 0, stream>>>(h, batch, N, psum, pmax);
  k_pool2<<<G, 64, 0, stream>>>(psum, pmax, batch, N, gpool);
  k_head<<<G, 64, 0, stream>>>(gpool, W1, b1, W2, b2, out);
}

// Round 7
// 465.619 us; speedup vs baseline: 1.0096x; 1.0096x over previous
//
#include <hip/hip_runtime.h>
#include <math.h>

#define DIN 128
#define HD 64
#define NEG 0.2f

__device__ __forceinline__ float sigmoidf_(float x) { return 1.f / (1.f + __expf(-x)); }
__device__ __forceinline__ float tanhf_(float x)    { return 2.f / (1.f + __expf(-2.f*x)) - 1.f; }

// ---------------- CSR build ----------------
__global__ void k_count(const int* __restrict__ dst, int E, int* __restrict__ deg) {
  int e = blockIdx.x*256 + threadIdx.x;
  if (e < E) atomicAdd(&deg[dst[e]], 1);
}

__global__ void k_scan1(const int* __restrict__ deg, int n, int* __restrict__ rowst, int* __restrict__ bsum) {
  __shared__ int s[256];
  int i = blockIdx.x*256 + threadIdx.x;
  int v = (i < n) ? deg[i] : 0;
  s[threadIdx.x] = v;
  __syncthreads();
  for (int off = 1; off < 256; off <<= 1) {
    int t = (threadIdx.x >= off) ? s[threadIdx.x - off] : 0;
    __syncthreads();
    s[threadIdx.x] += t;
    __syncthreads();
  }
  if (i < n) rowst[i] = s[threadIdx.x] - v;
  if (threadIdx.x == 255) bsum[blockIdx.x] = s[255];
}

__global__ void k_scan2(int* bsum, int nb) {
  __shared__ int s[256];
  int v = (threadIdx.x < nb) ? bsum[threadIdx.x] : 0;
  s[threadIdx.x] = v;
  __syncthreads();
  for (int off = 1; off < 256; off <<= 1) {
    int t = (threadIdx.x >= off) ? s[threadIdx.x - off] : 0;
    __syncthreads();
    s[threadIdx.x] += t;
    __syncthreads();
  }
  if (threadIdx.x < nb) bsum[threadIdx.x] = s[threadIdx.x] - v;
}

__global__ void k_scan3(int* __restrict__ rowst, const int* __restrict__ bsum, int n, int E, int* __restrict__ deg) {
  int i = blockIdx.x*256 + threadIdx.x;
  if (i < n) { rowst[i] += bsum[blockIdx.x]; deg[i] = 0; }
  if (i == 0) rowst[n] = E;
}

__global__ void k_scatter(const int* __restrict__ src, const int* __restrict__ dst, int E,
                          const int* __restrict__ rowst, int* __restrict__ fill, int* __restrict__ csr) {
  int e = blockIdx.x*256 + threadIdx.x;
  if (e < E) {
    int d = dst[e];
    int pos = rowst[d] + atomicAdd(&fill[d], 1);
    csr[pos] = src[e];
  }
}

// ---------------- GRU weight re-layout ----------------
// B[k][c], k in [0,128): k<64 -> m-row (Wi), k>=64 -> h-row (Wh).
// c = j*4 + gate; gate 0: r-sum, 1: z-sum, 2: gi_n (Wi only), 3: gh_n (Wh only)
__global__ void k_wt2(const float* __restrict__ Wi, const float* __restrict__ Wh,
                      const float* __restrict__ bi, const float* __restrict__ bh,
                      float* __restrict__ B, float* __restrict__ bc) {
  int i = blockIdx.x*256 + threadIdx.x;
  if (i < 128*256) {
    int k = i >> 8, c = i & 255;
    int j = c >> 2, g = c & 3;
    float v;
    if (g == 0)      v = (k < 64) ? Wi[k*(3*HD) + j]        : Wh[(k-64)*(3*HD) + j];
    else if (g == 1) v = (k < 64) ? Wi[k*(3*HD) + HD + j]   : Wh[(k-64)*(3*HD) + HD + j];
    else if (g == 2) v = (k < 64) ? Wi[k*(3*HD) + 2*HD + j] : 0.f;
    else             v = (k < 64) ? 0.f                     : Wh[(k-64)*(3*HD) + 2*HD + j];
    B[i] = v;
  }
  if (i < 256) {
    int j = i >> 2, g = i & 3;
    float v;
    if (g == 0)      v = bi[j] + bh[j];
    else if (g == 1) v = bi[HD + j] + bh[HD + j];
    else if (g == 2) v = bi[2*HD + j];
    else             v = bh[2*HD + j];
    bc[i] = v;
  }
}

// ---------------- input projection as register-blocked GEMM (M=32 tile) ----------------
__global__ void __launch_bounds__(256) k_proj2(const float* __restrict__ x, const float* __restrict__ Win,
                       const float* __restrict__ bin, const float* __restrict__ aatt, int n,
                       float* __restrict__ h, float* __restrict__ ssrc, float* __restrict__ sdst) {
  __shared__ float A[DIN][32];   // 16KB
  int m_base = blockIdx.x * 32;
  int tx = threadIdx.x;
  {
    int m = tx & 31;
    int kq8 = tx >> 5;           // 0..7
    int node = m_base + m;
    bool valid = node < n;
    const float4* x4 = (const float4*)(x + (size_t)node*DIN);
#pragma unroll
    for (int it = 0; it < 4; ++it) {
      int kq = kq8*4 + it;       // 0..31
      int k0 = kq*4;
      float4 v = make_float4(0.f,0.f,0.f,0.f);
      if (valid) v = x4[kq];
      A[k0+0][m] = v.x; A[k0+1][m] = v.y; A[k0+2][m] = v.z; A[k0+3][m] = v.w;
    }
  }
  __syncthreads();

  int c_idx = tx & 31;           // 2 cols each
  int m_idx = tx >> 5;           // 8 node groups of 4
  int c0 = c_idx * 2;
  int m0 = m_idx * 4;

  float acc[4][2];
#pragma unroll
  for (int a = 0; a < 4; ++a) { acc[a][0] = 0.f; acc[a][1] = 0.f; }

#pragma unroll 4
  for (int k = 0; k < DIN; ++k) {
    float2 b = *(const float2*)(Win + k*HD + c0);
    float4 a0 = *(const float4*)(&A[k][m0]);
    float av[4] = {a0.x,a0.y,a0.z,a0.w};
#pragma unroll
    for (int a = 0; a < 4; ++a) { acc[a][0] += av[a]*b.x; acc[a][1] += av[a]*b.y; }
  }

  float b0 = bin[c0], b1 = bin[c0+1];
  float a_s0 = aatt[c0],    a_s1 = aatt[c0+1];
  float a_d0 = aatt[HD+c0], a_d1 = aatt[HD+c0+1];

#pragma unroll
  for (int a = 0; a < 4; ++a) {
    int node = m_base + m0 + a;
    float v0 = fmaxf(acc[a][0] + b0, 0.f);
    float v1 = fmaxf(acc[a][1] + b1, 0.f);
    if (node < n) {
      h[(size_t)node*HD + c0]   = v0;
      h[(size_t)node*HD + c0+1] = v1;
    }
    float ps = v0*a_s0 + v1*a_s1;
    float pd = v0*a_d0 + v1*a_d1;
#pragma unroll
    for (int off = 16; off; off >>= 1) { ps += __shfl_xor(ps, off); pd += __shfl_xor(pd, off); }
    if (c_idx == 0 && node < n) { ssrc[node] = ps; sdst[node] = pd; }
  }
}

// ---------------- attention scores: 16-lane group per node ----------------
__global__ void k_score(const float* __restrict__ ssrc, const float* __restrict__ sdst,
                        const int* __restrict__ rowst, const int* __restrict__ csr, int n,
                        float* __restrict__ alpha, float* __restrict__ z) {
  int g16 = threadIdx.x >> 4;
  int l16 = threadIdx.x & 15;
  int node = blockIdx.x*16 + g16;
  if (node >= n) return;
  int s0 = rowst[node], s1 = rowst[node+1];
  float sdv = sdst[node];
  float mx = -INFINITY;
  for (int i = s0 + l16; i < s1; i += 16) {
    float sc = ssrc[csr[i]] + sdv;
    sc = (sc > 0.f) ? sc : NEG*sc;
    alpha[i] = sc;
    mx = fmaxf(mx, sc);
  }
#pragma unroll
  for (int off = 8; off; off >>= 1) mx = fmaxf(mx, __shfl_xor(mx, off));
  float zs = 0.f;
  for (int i = s0 + l16; i < s1; i += 16) {
    float e = __expf(alpha[i] - mx);
    alpha[i] = e;
    zs += e;
  }
#pragma unroll
  for (int off = 8; off; off >>= 1) zs += __shfl_xor(zs, off);
  if (l16 == 0) z[node] = zs;
}

// ---------------- gather pass v4: 16 lanes per node, float4/lane, 4 edges in flight ----------------
__global__ void k_agg4(const float* __restrict__ h, const float* __restrict__ alpha,
                       const float* __restrict__ z, const int* __restrict__ rowst,
                       const int* __restrict__ csr, int n, float* __restrict__ mout) {
  int g16 = threadIdx.x >> 4;     // 16 groups per block
  int l16 = threadIdx.x & 15;
  int node = blockIdx.x*16 + g16;
  if (node >= n) return;
  int s0 = rowst[node], s1 = rowst[node+1];
  float4 acc0 = make_float4(0.f,0.f,0.f,0.f);
  float4 acc1 = make_float4(0.f,0.f,0.f,0.f);
  float4 acc2 = make_float4(0.f,0.f,0.f,0.f);
  float4 acc3 = make_float4(0.f,0.f,0.f,0.f);
  int i = s0;
  for (; i + 3 < s1; i += 4) {
    int u0 = csr[i], u1 = csr[i+1], u2 = csr[i+2], u3 = csr[i+3];
    float a0 = alpha[i], a1 = alpha[i+1], a2 = alpha[i+2], a3 = alpha[i+3];
    float4 h0 = *((const float4*)(h + (size_t)u0*HD) + l16);
    float4 h1 = *((const float4*)(h + (size_t)u1*HD) + l16);
    float4 h2 = *((const float4*)(h + (size_t)u2*HD) + l16);
    float4 h3 = *((const float4*)(h + (size_t)u3*HD) + l16);
    acc0.x += a0*h0.x; acc0.y += a0*h0.y; acc0.z += a0*h0.z; acc0.w += a0*h0.w;
    acc1.x += a1*h1.x; acc1.y += a1*h1.y; acc1.z += a1*h1.z; acc1.w += a1*h1.w;
    acc2.x += a2*h2.x; acc2.y += a2*h2.y; acc2.z += a2*h2.z; acc2.w += a2*h2.w;
    acc3.x += a3*h3.x; acc3.y += a3*h3.y; acc3.z += a3*h3.z; acc3.w += a3*h3.w;
  }
  for (; i < s1; ++i) {
    float a0 = alpha[i];
    float4 h0 = *((const float4*)(h + (size_t)csr[i]*HD) + l16);
    acc0.x += a0*h0.x; acc0.y += a0*h0.y; acc0.z += a0*h0.z; acc0.w += a0*h0.w;
  }
  float zi = 1.f / (z[node] + 1e-16f);
  float4 r;
  r.x = ((acc0.x + acc1.x) + (acc2.x + acc3.x)) * zi;
  r.y = ((acc0.y + acc1.y) + (acc2.y + acc3.y)) * zi;
  r.z = ((acc0.z + acc1.z) + (acc2.z + acc3.z)) * zi;
  r.w = ((acc0.w + acc1.w) + (acc2.w + acc3.w)) * zi;
  *((float4*)(mout + (size_t)node*HD) + l16) = r;
}

// ---------------- GRU GEMM v5: lane-per-column, M=32 tile (occupancy fix) ----------------
// 256 threads = 4 waves, grid N/32. Lane owns j = lane (cols c0=4*lane).
// Each thread computes 8 nodes (m0 = (tx>>6)*8). Per k: ONE coalesced B float4 per lane
// (1KB unique per wave) + 2 broadcast LDS float4 of A. acc[8][4] ~ 74 VGPR.
__global__ void __launch_bounds__(256, 6) k_gru5(const float* __restrict__ mm, float* __restrict__ h,
                      const float* __restrict__ B, const float* __restrict__ bc,
                      const float* __restrict__ aatt, int n,
                      float* __restrict__ ssrc, float* __restrict__ sdst) {
  __shared__ float A[128][32];   // 16KB: rows 0..63 = m, rows 64..127 = h
  int m_base = blockIdx.x * 32;
  int tx = threadIdx.x;
  {
    int m = tx & 31;
    int kq8 = tx >> 5;           // 0..7
    int node = m_base + m;
    bool valid = node < n;
    const float4* m4 = (const float4*)(mm + (size_t)node*HD);
    const float4* h4 = (const float4*)(h  + (size_t)node*HD);
#pragma unroll
    for (int it = 0; it < 4; ++it) {
      int kq = kq8*4 + it;       // 0..31
      int k0 = kq*4;
      float4 v = make_float4(0.f,0.f,0.f,0.f);
      if (valid) v = (kq < 16) ? m4[kq] : h4[kq - 16];
      A[k0+0][m] = v.x; A[k0+1][m] = v.y; A[k0+2][m] = v.z; A[k0+3][m] = v.w;
    }
  }
  __syncthreads();

  int lane = tx & 63;            // j = lane
  int m0 = (tx >> 6) * 8;        // 8 nodes per thread

  float acc[8][4];
#pragma unroll
  for (int a = 0; a < 8; ++a)
#pragma unroll
    for (int b = 0; b < 4; ++b) acc[a][b] = 0.f;

  const float4* Bv = (const float4*)B;   // row k: Bv[k*64 + lane]

  // prologue: k = 0
  float4 bcur = Bv[lane];
  float4 ac0 = *(const float4*)(&A[0][m0]);
  float4 ac1 = *(const float4*)(&A[0][m0+4]);

#pragma unroll 1
  for (int k = 0; k < 127; ++k) {
    float4 bn  = Bv[(size_t)(k+1)*64 + lane];
    float4 an0 = *(const float4*)(&A[k+1][m0]);
    float4 an1 = *(const float4*)(&A[k+1][m0+4]);
    float av[8] = {ac0.x,ac0.y,ac0.z,ac0.w, ac1.x,ac1.y,ac1.z,ac1.w};
#pragma unroll
    for (int a = 0; a < 8; ++a) {
      acc[a][0] += av[a]*bcur.x;
      acc[a][1] += av[a]*bcur.y;
      acc[a][2] += av[a]*bcur.z;
      acc[a][3] += av[a]*bcur.w;
    }
    bcur = bn; ac0 = an0; ac1 = an1;
  }
  { // k = 127
    float av[8] = {ac0.x,ac0.y,ac0.z,ac0.w, ac1.x,ac1.y,ac1.z,ac1.w};
#pragma unroll
    for (int a = 0; a < 8; ++a) {
      acc[a][0] += av[a]*bcur.x;
      acc[a][1] += av[a]*bcur.y;
      acc[a][2] += av[a]*bcur.z;
      acc[a][3] += av[a]*bcur.w;
    }
  }

  float4 bcr = *(const float4*)(bc + 4*lane);
  float a_s = aatt[lane];
  float a_d = aatt[HD + lane];

#pragma unroll
  for (int a = 0; a < 8; ++a) {
    int node = m_base + m0 + a;
    float hold = (node < n) ? h[(size_t)node*HD + lane] : 0.f;
    float r   = acc[a][0] + bcr.x;
    float zz  = acc[a][1] + bcr.y;
    float gin = acc[a][2] + bcr.z;
    float ghn = acc[a][3] + bcr.w;
    float rg = sigmoidf_(r);
    float zg = sigmoidf_(zz);
    float ng = tanhf_(gin + rg*ghn);
    float hnew = (1.f - zg)*ng + zg*hold;
    if (node < n) h[(size_t)node*HD + lane] = hnew;
    float ps = hnew * a_s;
    float pd = hnew * a_d;
#pragma unroll
    for (int off = 32; off; off >>= 1) { ps += __shfl_xor(ps, off); pd += __shfl_xor(pd, off); }
    if (lane == 0 && node < n) { ssrc[node] = ps; sdst[node] = pd; }
  }
}

// ---------------- pooling: two-stage ----------------
__device__ __forceinline__ int lower_bound_i(const int* a, int n, int key) {
  int lo = 0, hi = n;
  while (lo < hi) { int mid = (lo + hi) >> 1; if (a[mid] < key) lo = mid + 1; else hi = mid; }
  return lo;
}

__global__ void k_pool1(const float* __restrict__ h, const int* __restrict__ batch, int n,
                        float* __restrict__ psum, float* __restrict__ pmax) {
  int g = blockIdx.x >> 3, slice = blockIdx.x & 7;
  int lane = threadIdx.x;            // 64 lanes = HD
  int lo = lower_bound_i(batch, n, g);
  int hi = lower_bound_i(batch, n, g + 1);
  int span = hi - lo;
  int s0 = lo + (int)(((long long)span * slice) >> 3);
  int s1 = lo + (int)(((long long)span * (slice + 1)) >> 3);
  float sum0 = 0.f, sum1 = 0.f, sum2 = 0.f, sum3 = 0.f;
  float mx0 = -INFINITY, mx1 = -INFINITY, mx2 = -INFINITY, mx3 = -INFINITY;
  int i = s0;
  for (; i + 3 < s1; i += 4) {
    float v0 = h[(size_t)(i+0)*HD + lane];
    float v1 = h[(size_t)(i+1)*HD + lane];
    float v2 = h[(size_t)(i+2)*HD + lane];
    float v3 = h[(size_t)(i+3)*HD + lane];
    sum0 += v0; sum1 += v1; sum2 += v2; sum3 += v3;
    mx0 = fmaxf(mx0, v0); mx1 = fmaxf(mx1, v1); mx2 = fmaxf(mx2, v2); mx3 = fmaxf(mx3, v3);
  }
  for (; i < s1; ++i) {
    float v = h[(size_t)i*HD + lane];
    sum0 += v; mx0 = fmaxf(mx0, v);
  }
  float sum = (sum0 + sum1) + (sum2 + sum3);
  float mx = fmaxf(fmaxf(mx0, mx1), fmaxf(mx2, mx3));
  psum[(size_t)blockIdx.x*HD + lane] = sum;
  pmax[(size_t)blockIdx.x*HD + lane] = mx;
}

__global__ void k_pool2(const float* __restrict__ psum, const float* __restrict__ pmax,
                        const int* __restrict__ batch, int n, float* __restrict__ gpool) {
  int g = blockIdx.x;
  int lane = threadIdx.x;
  int lo = lower_bound_i(batch, n, g);
  int hi = lower_bound_i(batch, n, g + 1);
  int cnt = hi - lo;
  float sum = 0.f, mx = -INFINITY;
#pragma unroll
  for (int s = 0; s < 8; ++s) {
    sum += psum[(size_t)(g*8+s)*HD + lane];
    mx = fmaxf(mx, pmax[(size_t)(g*8+s)*HD + lane]);
  }
  float mean = sum / fmaxf((float)cnt, 1.f);
  if (cnt <= 0 || !isfinite(mx)) mx = 0.f;
  gpool[(size_t)g*2*HD + lane] = mean;
  gpool[(size_t)g*2*HD + HD + lane] = mx;
}

// ---------------- MLP head (block per graph, one wave) ----------------
__global__ void k_head(const float* __restrict__ gpool, const float* __restrict__ W1,
                       const float* __restrict__ b1, const float* __restrict__ W2,
                       const float* __restrict__ b2, float* __restrict__ out) {
  int g = blockIdx.x, j = threadIdx.x;
  const float* gr = gpool + (size_t)g*2*HD;
  float acc = b1[j];
#pragma unroll
  for (int k = 0; k < 2*HD; ++k) acc += gr[k] * W1[k*HD + j];
  acc = fmaxf(acc, 0.f);
  float v = acc * W2[j];
#pragma unroll
  for (int off = 32; off; off >>= 1) v += __shfl_xor(v, off);
  if (j == 0) out[g] = v + b2[0];
}

extern "C" void kernel_launch(void* const* d_in, const int* in_sizes, int n_in,
                              void* d_out, int out_size, void* d_ws, size_t ws_size,
                              hipStream_t stream) {
  const float* x     = (const float*)d_in[0];
  const int*   ei    = (const int*)d_in[1];
  const int*   batch = (const int*)d_in[2];
  const float* Win   = (const float*)d_in[3];
  const float* bin   = (const float*)d_in[4];
  const float* aatt  = (const float*)d_in[5];
  const float* Wi    = (const float*)d_in[6];
  const float* Wh    = (const float*)d_in[7];
  const float* bi    = (const float*)d_in[8];
  const float* bh    = (const float*)d_in[9];
  const float* W1    = (const float*)d_in[10];
  const float* b1    = (const float*)d_in[11];
  const float* W2    = (const float*)d_in[12];
  const float* b2    = (const float*)d_in[13];
  float* out = (float*)d_out;

  int N = in_sizes[0] / DIN;
  int E = in_sizes[1] / 2;
  int G = out_size;

  const int* srcp = ei;
  const int* dstp = ei + E;

  char* base = (char*)d_ws;
  size_t off = 0;
  auto alloc = [&](size_t bytes) -> char* {
    char* p = base + off;
    off += (bytes + 255) & ~(size_t)255;
    return p;
  };
  float* h     = (float*)alloc((size_t)N*HD*4);
  float* mbuf  = (float*)alloc((size_t)N*HD*4);
  float* ssrc  = (float*)alloc((size_t)N*4);
  float* sdst  = (float*)alloc((size_t)N*4);
  int*   deg   = (int*)  alloc((size_t)N*4);
  int*   rowst = (int*)  alloc((size_t)(N+1)*4);
  int*   csr   = (int*)  alloc((size_t)E*4);
  float* alpha = (float*)alloc((size_t)E*4);
  float* zbuf  = (float*)alloc((size_t)N*4);
  float* B     = (float*)alloc((size_t)128*256*4);
  float* bc    = (float*)alloc((size_t)256*4);
  float* gpool = (float*)alloc((size_t)G*2*HD*4);
  float* psum  = (float*)alloc((size_t)G*8*HD*4);
  float* pmax  = (float*)alloc((size_t)G*8*HD*4);
  int*   bsum  = (int*)  alloc(1024);
  (void)ws_size; (void)n_in;

  int nbN = (N + 255)/256, nbE = (E + 255)/256;

  hipMemsetAsync(deg, 0, (size_t)N*4, stream);
  k_count<<<nbE, 256, 0, stream>>>(dstp, E, deg);
  k_scan1<<<nbN, 256, 0, stream>>>(deg, N, rowst, bsum);
  k_scan2<<<1, 256, 0, stream>>>(bsum, nbN);
  k_scan3<<<nbN, 256, 0, stream>>>(rowst, bsum, N, E, deg);
  k_scatter<<<nbE, 256, 0, stream>>>(srcp, dstp, E, rowst, deg, csr);
  k_wt2<<<(128*256 + 255)/256, 256, 0, stream>>>(Wi, Wh, bi, bh, B, bc);
  k_proj2<<<(N + 31)/32, 256, 0, stream>>>(x, Win, bin, aatt, N, h, ssrc, sdst);
  for (int t = 0; t < 3; ++t) {
    k_score<<<(N + 15)/16, 256, 0, stream>>>(ssrc, sdst, rowst, csr, N, alpha, zbuf);
    k_agg4<<<(N + 15)/16, 256, 0, stream>>>(h, alpha, zbuf, rowst, csr, N, mbuf);
    k_gru5<<<(N + 31)/32, 256, 0, stream>>>(mbuf, h, B, bc, aatt, N, ssrc, sdst);
  }
  k_pool1<<<G*8, 64, 0, stream>>>(h, batch, N, psum, pmax);
  k_pool2<<<G, 64, 0, stream>>>(psum, pmax, batch, N, gpool);
  k_head<<<G, 64, 0, stream>>>(gpool, W1, b1, W2, b2, out);
}

// Round 8
// 424.977 us; speedup vs baseline: 1.1061x; 1.0956x over previous
//
#include <hip/hip_runtime.h>
#include <math.h>

#define DIN 128
#define HD 64
#define NEG 0.2f

__device__ __forceinline__ float sigmoidf_(float x) { return 1.f / (1.f + __expf(-x)); }
__device__ __forceinline__ float tanhf_(float x)    { return 2.f / (1.f + __expf(-2.f*x)) - 1.f; }

// ---------------- CSR build ----------------
__global__ void k_count(const int* __restrict__ dst, int E, int* __restrict__ deg) {
  int e = blockIdx.x*256 + threadIdx.x;
  if (e < E) atomicAdd(&deg[dst[e]], 1);
}

__global__ void k_scan1(const int* __restrict__ deg, int n, int* __restrict__ rowst, int* __restrict__ bsum) {
  __shared__ int s[256];
  int i = blockIdx.x*256 + threadIdx.x;
  int v = (i < n) ? deg[i] : 0;
  s[threadIdx.x] = v;
  __syncthreads();
  for (int off = 1; off < 256; off <<= 1) {
    int t = (threadIdx.x >= off) ? s[threadIdx.x - off] : 0;
    __syncthreads();
    s[threadIdx.x] += t;
    __syncthreads();
  }
  if (i < n) rowst[i] = s[threadIdx.x] - v;
  if (threadIdx.x == 255) bsum[blockIdx.x] = s[255];
}

__global__ void k_scan2(int* bsum, int nb) {
  __shared__ int s[256];
  int v = (threadIdx.x < nb) ? bsum[threadIdx.x] : 0;
  s[threadIdx.x] = v;
  __syncthreads();
  for (int off = 1; off < 256; off <<= 1) {
    int t = (threadIdx.x >= off) ? s[threadIdx.x - off] : 0;
    __syncthreads();
    s[threadIdx.x] += t;
    __syncthreads();
  }
  if (threadIdx.x < nb) bsum[threadIdx.x] = s[threadIdx.x] - v;
}

__global__ void k_scan3(int* __restrict__ rowst, const int* __restrict__ bsum, int n, int E, int* __restrict__ deg) {
  int i = blockIdx.x*256 + threadIdx.x;
  if (i < n) { rowst[i] += bsum[blockIdx.x]; deg[i] = 0; }
  if (i == 0) rowst[n] = E;
}

__global__ void k_scatter(const int* __restrict__ src, const int* __restrict__ dst, int E,
                          const int* __restrict__ rowst, int* __restrict__ fill, int* __restrict__ csr) {
  int e = blockIdx.x*256 + threadIdx.x;
  if (e < E) {
    int d = dst[e];
    int pos = rowst[d] + atomicAdd(&fill[d], 1);
    csr[pos] = src[e];
  }
}

// ---------------- GRU weight re-layout ----------------
// B[k][c], k in [0,128): k<64 -> m-row (Wi), k>=64 -> h-row (Wh).
// c = j*4 + gate; gate 0: r-sum, 1: z-sum, 2: gi_n (Wi only), 3: gh_n (Wh only)
__global__ void k_wt2(const float* __restrict__ Wi, const float* __restrict__ Wh,
                      const float* __restrict__ bi, const float* __restrict__ bh,
                      float* __restrict__ B, float* __restrict__ bc) {
  int i = blockIdx.x*256 + threadIdx.x;
  if (i < 128*256) {
    int k = i >> 8, c = i & 255;
    int j = c >> 2, g = c & 3;
    float v;
    if (g == 0)      v = (k < 64) ? Wi[k*(3*HD) + j]        : Wh[(k-64)*(3*HD) + j];
    else if (g == 1) v = (k < 64) ? Wi[k*(3*HD) + HD + j]   : Wh[(k-64)*(3*HD) + HD + j];
    else if (g == 2) v = (k < 64) ? Wi[k*(3*HD) + 2*HD + j] : 0.f;
    else             v = (k < 64) ? 0.f                     : Wh[(k-64)*(3*HD) + 2*HD + j];
    B[i] = v;
  }
  if (i < 256) {
    int j = i >> 2, g = i & 3;
    float v;
    if (g == 0)      v = bi[j] + bh[j];
    else if (g == 1) v = bi[HD + j] + bh[HD + j];
    else if (g == 2) v = bi[2*HD + j];
    else             v = bh[2*HD + j];
    bc[i] = v;
  }
}

// ---------------- input projection as register-blocked GEMM (M=32 tile) ----------------
__global__ void __launch_bounds__(256) k_proj2(const float* __restrict__ x, const float* __restrict__ Win,
                       const float* __restrict__ bin, const float* __restrict__ aatt, int n,
                       float* __restrict__ h, float* __restrict__ ssrc, float* __restrict__ sdst) {
  __shared__ float A[DIN][32];   // 16KB
  int m_base = blockIdx.x * 32;
  int tx = threadIdx.x;
  {
    int m = tx & 31;
    int kq8 = tx >> 5;           // 0..7
    int node = m_base + m;
    bool valid = node < n;
    const float4* x4 = (const float4*)(x + (size_t)node*DIN);
#pragma unroll
    for (int it = 0; it < 4; ++it) {
      int kq = kq8*4 + it;       // 0..31
      int k0 = kq*4;
      float4 v = make_float4(0.f,0.f,0.f,0.f);
      if (valid) v = x4[kq];
      A[k0+0][m] = v.x; A[k0+1][m] = v.y; A[k0+2][m] = v.z; A[k0+3][m] = v.w;
    }
  }
  __syncthreads();

  int c_idx = tx & 31;           // 2 cols each
  int m_idx = tx >> 5;           // 8 node groups of 4
  int c0 = c_idx * 2;
  int m0 = m_idx * 4;

  float acc[4][2];
#pragma unroll
  for (int a = 0; a < 4; ++a) { acc[a][0] = 0.f; acc[a][1] = 0.f; }

#pragma unroll 4
  for (int k = 0; k < DIN; ++k) {
    float2 b = *(const float2*)(Win + k*HD + c0);
    float4 a0 = *(const float4*)(&A[k][m0]);
    float av[4] = {a0.x,a0.y,a0.z,a0.w};
#pragma unroll
    for (int a = 0; a < 4; ++a) { acc[a][0] += av[a]*b.x; acc[a][1] += av[a]*b.y; }
  }

  float b0 = bin[c0], b1 = bin[c0+1];
  float a_s0 = aatt[c0],    a_s1 = aatt[c0+1];
  float a_d0 = aatt[HD+c0], a_d1 = aatt[HD+c0+1];

#pragma unroll
  for (int a = 0; a < 4; ++a) {
    int node = m_base + m0 + a;
    float v0 = fmaxf(acc[a][0] + b0, 0.f);
    float v1 = fmaxf(acc[a][1] + b1, 0.f);
    if (node < n) {
      h[(size_t)node*HD + c0]   = v0;
      h[(size_t)node*HD + c0+1] = v1;
    }
    float ps = v0*a_s0 + v1*a_s1;
    float pd = v0*a_d0 + v1*a_d1;
#pragma unroll
    for (int off = 16; off; off >>= 1) { ps += __shfl_xor(ps, off); pd += __shfl_xor(pd, off); }
    if (c_idx == 0 && node < n) { ssrc[node] = ps; sdst[node] = pd; }
  }
}

// ---------------- fused score + softmax + gather: 16 lanes per node ----------------
// Fast path (deg<=64): raw scores and csr u's in 4 static regs/lane, exp+z in-register,
// gather pass shfl-broadcasts alpha. No alpha/z global round-trip.
__global__ void __launch_bounds__(256) k_sagg(const float* __restrict__ h, const float* __restrict__ ssrc,
                       const float* __restrict__ sdst, const int* __restrict__ rowst,
                       const int* __restrict__ csr, int n, float* __restrict__ mout) {
  int g16 = threadIdx.x >> 4;
  int l16 = threadIdx.x & 15;
  int node = blockIdx.x*16 + g16;
  if (node >= n) return;
  int s0 = rowst[node], s1 = rowst[node+1];
  int deg = s1 - s0;
  float4 acc = make_float4(0.f,0.f,0.f,0.f);
  if (deg <= 0) {
    *((float4*)(mout + (size_t)node*HD) + l16) = acc;
    return;
  }
  float sdv = sdst[node];

  if (deg <= 64) {
    float areg[4];
    int   ureg[4];
    float mx = -INFINITY;
#pragma unroll
    for (int c = 0; c < 4; ++c) {
      int idx = s0 + c*16 + l16;
      int uu = csr[(idx < s1) ? idx : s0];    // clamped safe read
      ureg[c] = uu;
      float sc = -INFINITY;
      if (idx < s1) {
        sc = ssrc[uu] + sdv;
        sc = (sc > 0.f) ? sc : NEG*sc;
      }
      areg[c] = sc;
      mx = fmaxf(mx, sc);
    }
#pragma unroll
    for (int off = 8; off; off >>= 1) mx = fmaxf(mx, __shfl_xor(mx, off, 16));
    float zs = 0.f;
#pragma unroll
    for (int c = 0; c < 4; ++c) {
      float e = __expf(areg[c] - mx);          // exp(-inf - mx) = 0 for invalid slots
      areg[c] = e;
      zs += e;
    }
#pragma unroll
    for (int off = 8; off; off >>= 1) zs += __shfl_xor(zs, off, 16);
    float zi = 1.f / (zs + 1e-16f);

#pragma unroll
    for (int c = 0; c < 4; ++c) {
      int base = s0 + c*16;
      if (base < s1) {
        int cnt = s1 - base;                  // >=1; loop caps at 16
#pragma unroll
        for (int e = 0; e < 16; ++e) {
          if (e < cnt) {
            int   ue = __shfl(ureg[c], e, 16);
            float ae = __shfl(areg[c], e, 16);
            float4 hv = *((const float4*)(h + (size_t)ue*HD) + l16);
            acc.x += ae*hv.x; acc.y += ae*hv.y; acc.z += ae*hv.z; acc.w += ae*hv.w;
          }
        }
      }
    }
    acc.x *= zi; acc.y *= zi; acc.z *= zi; acc.w *= zi;
  } else {
    // long-row fallback: streaming two-pass + serial gather
    float mx = -INFINITY;
    for (int i = s0 + l16; i < s1; i += 16) {
      float sc = ssrc[csr[i]] + sdv;
      sc = (sc > 0.f) ? sc : NEG*sc;
      mx = fmaxf(mx, sc);
    }
#pragma unroll
    for (int off = 8; off; off >>= 1) mx = fmaxf(mx, __shfl_xor(mx, off, 16));
    float zs = 0.f;
    for (int i = s0 + l16; i < s1; i += 16) {
      float sc = ssrc[csr[i]] + sdv;
      sc = (sc > 0.f) ? sc : NEG*sc;
      zs += __expf(sc - mx);
    }
#pragma unroll
    for (int off = 8; off; off >>= 1) zs += __shfl_xor(zs, off, 16);
    float zi = 1.f / (zs + 1e-16f);
    for (int i = s0; i < s1; ++i) {
      int u = csr[i];
      float sc = ssrc[u] + sdv;
      sc = (sc > 0.f) ? sc : NEG*sc;
      float p = __expf(sc - mx);
      float4 hv = *((const float4*)(h + (size_t)u*HD) + l16);
      acc.x += p*hv.x; acc.y += p*hv.y; acc.z += p*hv.z; acc.w += p*hv.w;
    }
    acc.x *= zi; acc.y *= zi; acc.z *= zi; acc.w *= zi;
  }
  *((float4*)(mout + (size_t)node*HD) + l16) = acc;
}

// ---------------- GRU GEMM v6: lane-per-column, M=32, compiler-scheduled unroll-4 ----------------
// 256 threads = 4 waves, grid N/32. Lane owns j = lane (cols c0=4*lane).
// Plain indexed loads + unroll 4: compiler renames registers across copies
// (no rotation movs) and batches 4 loads in flight.
__global__ void __launch_bounds__(256, 4) k_gru6(const float* __restrict__ mm, float* __restrict__ h,
                      const float* __restrict__ B, const float* __restrict__ bc,
                      const float* __restrict__ aatt, int n,
                      float* __restrict__ ssrc, float* __restrict__ sdst) {
  __shared__ float A[128][32];   // 16KB: rows 0..63 = m, rows 64..127 = h
  int m_base = blockIdx.x * 32;
  int tx = threadIdx.x;
  {
    int m = tx & 31;
    int kq8 = tx >> 5;           // 0..7
    int node = m_base + m;
    bool valid = node < n;
    const float4* m4 = (const float4*)(mm + (size_t)node*HD);
    const float4* h4 = (const float4*)(h  + (size_t)node*HD);
#pragma unroll
    for (int it = 0; it < 4; ++it) {
      int kq = kq8*4 + it;       // 0..31
      int k0 = kq*4;
      float4 v = make_float4(0.f,0.f,0.f,0.f);
      if (valid) v = (kq < 16) ? m4[kq] : h4[kq - 16];
      A[k0+0][m] = v.x; A[k0+1][m] = v.y; A[k0+2][m] = v.z; A[k0+3][m] = v.w;
    }
  }
  __syncthreads();

  int lane = tx & 63;            // j = lane
  int m0 = (tx >> 6) * 8;        // 8 nodes per thread

  float acc[8][4];
#pragma unroll
  for (int a = 0; a < 8; ++a)
#pragma unroll
    for (int b = 0; b < 4; ++b) acc[a][b] = 0.f;

  const float4* Bv = (const float4*)B + lane;   // row k: Bv[k*64]

#pragma unroll 4
  for (int k = 0; k < 128; ++k) {
    float4 b  = Bv[(size_t)k*64];
    float4 a0 = *(const float4*)(&A[k][m0]);
    float4 a1 = *(const float4*)(&A[k][m0+4]);
    float av[8] = {a0.x,a0.y,a0.z,a0.w, a1.x,a1.y,a1.z,a1.w};
#pragma unroll
    for (int a = 0; a < 8; ++a) {
      acc[a][0] += av[a]*b.x;
      acc[a][1] += av[a]*b.y;
      acc[a][2] += av[a]*b.z;
      acc[a][3] += av[a]*b.w;
    }
  }

  float4 bcr = *(const float4*)(bc + 4*lane);
  float a_s = aatt[lane];
  float a_d = aatt[HD + lane];

#pragma unroll
  for (int a = 0; a < 8; ++a) {
    int node = m_base + m0 + a;
    float hold = (node < n) ? h[(size_t)node*HD + lane] : 0.f;
    float r   = acc[a][0] + bcr.x;
    float zz  = acc[a][1] + bcr.y;
    float gin = acc[a][2] + bcr.z;
    float ghn = acc[a][3] + bcr.w;
    float rg = sigmoidf_(r);
    float zg = sigmoidf_(zz);
    float ng = tanhf_(gin + rg*ghn);
    float hnew = (1.f - zg)*ng + zg*hold;
    if (node < n) h[(size_t)node*HD + lane] = hnew;
    float ps = hnew * a_s;
    float pd = hnew * a_d;
#pragma unroll
    for (int off = 32; off; off >>= 1) { ps += __shfl_xor(ps, off); pd += __shfl_xor(pd, off); }
    if (lane == 0 && node < n) { ssrc[node] = ps; sdst[node] = pd; }
  }
}

// ---------------- pooling: two-stage ----------------
__device__ __forceinline__ int lower_bound_i(const int* a, int n, int key) {
  int lo = 0, hi = n;
  while (lo < hi) { int mid = (lo + hi) >> 1; if (a[mid] < key) lo = mid + 1; else hi = mid; }
  return lo;
}

__global__ void k_pool1(const float* __restrict__ h, const int* __restrict__ batch, int n,
                        float* __restrict__ psum, float* __restrict__ pmax) {
  int g = blockIdx.x >> 3, slice = blockIdx.x & 7;
  int lane = threadIdx.x;            // 64 lanes = HD
  int lo = lower_bound_i(batch, n, g);
  int hi = lower_bound_i(batch, n, g + 1);
  int span = hi - lo;
  int s0 = lo + (int)(((long long)span * slice) >> 3);
  int s1 = lo + (int)(((long long)span * (slice + 1)) >> 3);
  float sum0 = 0.f, sum1 = 0.f, sum2 = 0.f, sum3 = 0.f;
  float mx0 = -INFINITY, mx1 = -INFINITY, mx2 = -INFINITY, mx3 = -INFINITY;
  int i = s0;
  for (; i + 3 < s1; i += 4) {
    float v0 = h[(size_t)(i+0)*HD + lane];
    float v1 = h[(size_t)(i+1)*HD + lane];
    float v2 = h[(size_t)(i+2)*HD + lane];
    float v3 = h[(size_t)(i+3)*HD + lane];
    sum0 += v0; sum1 += v1; sum2 += v2; sum3 += v3;
    mx0 = fmaxf(mx0, v0); mx1 = fmaxf(mx1, v1); mx2 = fmaxf(mx2, v2); mx3 = fmaxf(mx3, v3);
  }
  for (; i < s1; ++i) {
    float v = h[(size_t)i*HD + lane];
    sum0 += v; mx0 = fmaxf(mx0, v);
  }
  float sum = (sum0 + sum1) + (sum2 + sum3);
  float mx = fmaxf(fmaxf(mx0, mx1), fmaxf(mx2, mx3));
  psum[(size_t)blockIdx.x*HD + lane] = sum;
  pmax[(size_t)blockIdx.x*HD + lane] = mx;
}

__global__ void k_pool2(const float* __restrict__ psum, const float* __restrict__ pmax,
                        const int* __restrict__ batch, int n, float* __restrict__ gpool) {
  int g = blockIdx.x;
  int lane = threadIdx.x;
  int lo = lower_bound_i(batch, n, g);
  int hi = lower_bound_i(batch, n, g + 1);
  int cnt = hi - lo;
  float sum = 0.f, mx = -INFINITY;
#pragma unroll
  for (int s = 0; s < 8; ++s) {
    sum += psum[(size_t)(g*8+s)*HD + lane];
    mx = fmaxf(mx, pmax[(size_t)(g*8+s)*HD + lane]);
  }
  float mean = sum / fmaxf((float)cnt, 1.f);
  if (cnt <= 0 || !isfinite(mx)) mx = 0.f;
  gpool[(size_t)g*2*HD + lane] = mean;
  gpool[(size_t)g*2*HD + HD + lane] = mx;
}

// ---------------- MLP head (block per graph, one wave) ----------------
__global__ void k_head(const float* __restrict__ gpool, const float* __restrict__ W1,
                       const float* __restrict__ b1, const float* __restrict__ W2,
                       const float* __restrict__ b2, float* __restrict__ out) {
  int g = blockIdx.x, j = threadIdx.x;
  const float* gr = gpool + (size_t)g*2*HD;
  float acc = b1[j];
#pragma unroll
  for (int k = 0; k < 2*HD; ++k) acc += gr[k] * W1[k*HD + j];
  acc = fmaxf(acc, 0.f);
  float v = acc * W2[j];
#pragma unroll
  for (int off = 32; off; off >>= 1) v += __shfl_xor(v, off);
  if (j == 0) out[g] = v + b2[0];
}

extern "C" void kernel_launch(void* const* d_in, const int* in_sizes, int n_in,
                              void* d_out, int out_size, void* d_ws, size_t ws_size,
                              hipStream_t stream) {
  const float* x     = (const float*)d_in[0];
  const int*   ei    = (const int*)d_in[1];
  const int*   batch = (const int*)d_in[2];
  const float* Win   = (const float*)d_in[3];
  const float* bin   = (const float*)d_in[4];
  const float* aatt  = (const float*)d_in[5];
  const float* Wi    = (const float*)d_in[6];
  const float* Wh    = (const float*)d_in[7];
  const float* bi    = (const float*)d_in[8];
  const float* bh    = (const float*)d_in[9];
  const float* W1    = (const float*)d_in[10];
  const float* b1    = (const float*)d_in[11];
  const float* W2    = (const float*)d_in[12];
  const float* b2    = (const float*)d_in[13];
  float* out = (float*)d_out;

  int N = in_sizes[0] / DIN;
  int E = in_sizes[1] / 2;
  int G = out_size;

  const int* srcp = ei;
  const int* dstp = ei + E;

  char* base = (char*)d_ws;
  size_t off = 0;
  auto alloc = [&](size_t bytes) -> char* {
    char* p = base + off;
    off += (bytes + 255) & ~(size_t)255;
    return p;
  };
  float* h     = (float*)alloc((size_t)N*HD*4);
  float* mbuf  = (float*)alloc((size_t)N*HD*4);
  float* ssrc  = (float*)alloc((size_t)N*4);
  float* sdst  = (float*)alloc((size_t)N*4);
  int*   deg   = (int*)  alloc((size_t)N*4);
  int*   rowst = (int*)  alloc((size_t)(N+1)*4);
  int*   csr   = (int*)  alloc((size_t)E*4);
  float* B     = (float*)alloc((size_t)128*256*4);
  float* bc    = (float*)alloc((size_t)256*4);
  float* gpool = (float*)alloc((size_t)G*2*HD*4);
  float* psum  = (float*)alloc((size_t)G*8*HD*4);
  float* pmax  = (float*)alloc((size_t)G*8*HD*4);
  int*   bsum  = (int*)  alloc(1024);
  (void)ws_size; (void)n_in;

  int nbN = (N + 255)/256, nbE = (E + 255)/256;

  hipMemsetAsync(deg, 0, (size_t)N*4, stream);
  k_count<<<nbE, 256, 0, stream>>>(dstp, E, deg);
  k_scan1<<<nbN, 256, 0, stream>>>(deg, N, rowst, bsum);
  k_scan2<<<1, 256, 0, stream>>>(bsum, nbN);
  k_scan3<<<nbN, 256, 0, stream>>>(rowst, bsum, N, E, deg);
  k_scatter<<<nbE, 256, 0, stream>>>(srcp, dstp, E, rowst, deg, csr);
  k_wt2<<<(128*256 + 255)/256, 256, 0, stream>>>(Wi, Wh, bi, bh, B, bc);
  k_proj2<<<(N + 31)/32, 256, 0, stream>>>(x, Win, bin, aatt, N, h, ssrc, sdst);
  for (int t = 0; t < 3; ++t) {
    k_sagg<<<(N + 15)/16, 256, 0, stream>>>(h, ssrc, sdst, rowst, csr, N, mbuf);
    k_gru6<<<(N + 31)/32, 256, 0, stream>>>(mbuf, h, B, bc, aatt, N, ssrc, sdst);
  }
  k_pool1<<<G*8, 64, 0, stream>>>(h, batch, N, psum, pmax);
  k_pool2<<<G, 64, 0, stream>>>(psum, pmax, batch, N, gpool);
  k_head<<<G, 64, 0, stream>>>(gpool, W1, b1, W2, b2, out);
}